// Round 19
// baseline (2246.602 us; speedup 1.0000x reference)
//
#include <hip/hip_runtime.h>
#include <cmath>

#define NN 10000
#define EE 200000
#define BB 64
#define NCK 50
#define NCAND 5
#define TOKS 38
#define TITLE 30
#define GDIM 300
#define HH 20
#define DHD 20
#define DD 400
#define PP 200

typedef __attribute__((ext_vector_type(8))) short bh8;
typedef __attribute__((ext_vector_type(4))) float f32x4;

__device__ __forceinline__ float bf2f(unsigned short u) {
    return __uint_as_float(((unsigned int)u) << 16);
}
__device__ __forceinline__ unsigned short f2bf(float f) {
    unsigned int u = __float_as_uint(f);
    u += 0x7fffu + ((u >> 16) & 1u);
    return (unsigned short)(u >> 16);
}

// ---------------------------------------------------------------------------
// prep: Wt[1200][320] bf16 = concat(wq,wk,wv) transposed, k-padded with zeros
// ---------------------------------------------------------------------------
__global__ __launch_bounds__(256) void prep_wt(
    const float* __restrict__ wq, const float* __restrict__ wk,
    const float* __restrict__ wv, unsigned short* __restrict__ Wt)
{
    int i = blockIdx.x * 256 + threadIdx.x;
    if (i >= 1200 * 320) return;
    int n = i / 320, k = i % 320;
    int m = n / 400, nn = n % 400;
    const float* W = (m == 0) ? wq : ((m == 1) ? wk : wv);
    float v = (k < GDIM) ? W[(size_t)k * DD + nn] : 0.f;
    Wt[i] = f2bf(v);
}

// prep: [208][416] bf16 = [400][200] f32 transposed, padded (wp / uwp)
__global__ __launch_bounds__(256) void prep_wpt(
    const float* __restrict__ wp, unsigned short* __restrict__ wpT)
{
    int i = blockIdx.x * 256 + threadIdx.x;
    if (i >= 208 * 416) return;
    int n = i / 416, k = i % 416;
    float v = (n < PP && k < DD) ? wp[(size_t)k * PP + n] : 0.f;
    wpT[i] = f2bf(v);
}

// prep: wggT[3][400][424] bf16 = ggc_w[l] transposed, k-padded
__global__ __launch_bounds__(256) void prep_wgg(
    const float* __restrict__ ggc, unsigned short* __restrict__ wggT)
{
    int i = blockIdx.x * 256 + threadIdx.x;
    if (i >= 3 * 400 * 424) return;
    int l = i / (400*424), rem = i % (400*424);
    int n = rem / 424, k = rem % 424;
    float v = (k < DD) ? ggc[(size_t)l*DD*DD + (size_t)k*DD + n] : 0.f;
    wggT[i] = f2bf(v);
}

// prep: wihT/whhT [1200][424] bf16 transposed, k-padded
__global__ __launch_bounds__(256) void prep_gruw(
    const float* __restrict__ wih, const float* __restrict__ whh,
    unsigned short* __restrict__ wihT, unsigned short* __restrict__ whhT)
{
    int i = blockIdx.x * 256 + threadIdx.x;
    if (i >= 1200 * 424) return;
    int n = i / 424, k = i % 424;
    wihT[i] = f2bf((k < DD) ? wih[(size_t)k*1200 + n] : 0.f);
    whhT[i] = f2bf((k < DD) ? whh[(size_t)k*1200 + n] : 0.f);
}

// ---------------------------------------------------------------------------
// K1: fused news encoder (nodes + real + fake candidates, one grid).
// r18-PROVEN: register diet (afr 80 + ba[5] 40 + acc 8 ~ 150 live) +
// __launch_bounds__(256,3) -> 3 waves/SIMD, occupancy 35%, 1223 us.
// The unified VGPR+AGPR allocation (invisible in CSV VGPR_Count) was the
// 12-round occupancy cap. DO NOT touch this kernel.
// ---------------------------------------------------------------------------
__global__ __launch_bounds__(256, 3) void news_enc(
    const int* __restrict__ sub_x,
    const int* __restrict__ cand,
    const int* __restrict__ fcand,
    const float* __restrict__ glove,
    const unsigned short* __restrict__ Wt,     // [1200][320] bf16
    const unsigned short* __restrict__ wpT,    // [208][416] bf16
    const float* __restrict__ qp,
    float* __restrict__ x_enc,
    float* __restrict__ crnc,
    float* __restrict__ cfnc)
{
    __shared__ __align__(16) unsigned short uS[12288];         // 24576B
    __shared__ __align__(16) unsigned short outS[32*408 + 16]; // 26144B
    __shared__ int   tokS[32];
    __shared__ float alphaS[32];

    float* poolP = (float*)uS;   // valid after scr is dead

    const int tid  = threadIdx.x;
    const int item = blockIdx.x;
    const int w    = tid >> 6;        // wave 0..3
    const int lane = tid & 63;
    const int g    = lane >> 4;       // k-group 0..3
    const int l15  = lane & 15;

    const int* tsrc; float* odst;
    if (item < NN) {
        tsrc = sub_x + (size_t)item * TOKS;
        odst = x_enc + (size_t)item * DD;
    } else if (item < NN + BB*NCAND) {
        int li = item - NN;
        tsrc = cand + (size_t)li * TOKS;
        odst = crnc + (size_t)li * DD;
    } else {
        int li = item - NN - BB*NCAND;
        tsrc = fcand + (size_t)li * TOKS;
        odst = cfnc + (size_t)li * DD;
    }

    if (tid < TITLE) tokS[tid] = tsrc[tid];
    for (int i = tid; i < 12288/2; i += 256) ((unsigned int*)uS)[i] = 0u;
    for (int i = tid; i < (32*408+16)/2; i += 256) ((unsigned int*)outS)[i] = 0u;
    __syncthreads();

    // gather glove rows -> embS region of uS (rows 0..29, stride 328)
    for (int i = tid; i < TITLE * 75; i += 256) {
        int t = i / 75, g4 = i % 75;
        const float4 v = *(const float4*)&glove[(size_t)tokS[t] * GDIM + g4 * 4];
        uS[t*328 + g4*4+0] = f2bf(v.x);
        uS[t*328 + g4*4+1] = f2bf(v.y);
        uS[t*328 + g4*4+2] = f2bf(v.z);
        uS[t*328 + g4*4+3] = f2bf(v.w);
    }
    __syncthreads();

    // preload A-fragments into registers (80 VGPR); rows 30/31 are zero
    bh8 afr[2][10];
    #pragma unroll
    for (int mt = 0; mt < 2; ++mt)
        #pragma unroll
        for (int ks = 0; ks < 10; ++ks)
            afr[mt][ks] = *(const bh8*)&uS[(mt*16 + l15)*328 + ks*32 + g*8];
    __syncthreads();

    // re-zero uS: scr slices must start all-zero (NaN rule, r8 lesson)
    for (int i = tid; i < 12288/2; i += 256) ((unsigned int*)uS)[i] = 0u;
    __syncthreads();

    const float sc = 0.2236067977f;

    for (int hg = 0; hg < 5; ++hg) {
        // re-zero own q-slice pad cols 20..31 (P from previous hg wrote them)
        {
            unsigned short* qme = uS + w*1024;
            for (int i = lane; i < 32*6; i += 64) {
                int r = i / 6, c = 20 + (i % 6) * 2;
                *(unsigned int*)&qme[r*32 + c] = 0u;
            }
        }

        // ---- QKV: 15 n-tiles over 4 waves; ba[5] half-batched B-loads ----
        #pragma unroll
        for (int tt = 0; tt < 4; ++tt) {
            const int t = w*4 + tt;
            const bool valid = (t < 15);
            const int tc = valid ? t : 0;
            const int m = tc / 5, loc = tc % 5;
            const unsigned short* wb =
                Wt + (size_t)(m*400 + hg*80 + loc*16 + l15) * 320;
            f32x4 c0 = {0.f,0.f,0.f,0.f}, c1 = {0.f,0.f,0.f,0.f};
            bh8 ba[5];
            #pragma unroll
            for (int ks = 0; ks < 5; ++ks)
                ba[ks] = *(const bh8*)&wb[ks*32 + g*8];
            __builtin_amdgcn_sched_barrier(0);   // batch 1 pinned above
            #pragma unroll
            for (int ks = 0; ks < 5; ++ks) {
                c0 = __builtin_amdgcn_mfma_f32_16x16x32_bf16(afr[0][ks], ba[ks], c0, 0, 0, 0);
                c1 = __builtin_amdgcn_mfma_f32_16x16x32_bf16(afr[1][ks], ba[ks], c1, 0, 0, 0);
            }
            __builtin_amdgcn_sched_barrier(0);   // keep ba[] single-buffered
            #pragma unroll
            for (int ks = 0; ks < 5; ++ks)
                ba[ks] = *(const bh8*)&wb[(5+ks)*32 + g*8];
            __builtin_amdgcn_sched_barrier(0);   // batch 2 pinned above
            #pragma unroll
            for (int ks = 0; ks < 5; ++ks) {
                c0 = __builtin_amdgcn_mfma_f32_16x16x32_bf16(afr[0][5+ks], ba[ks], c0, 0, 0, 0);
                c1 = __builtin_amdgcn_mfma_f32_16x16x32_bf16(afr[1][5+ks], ba[ks], c1, 0, 0, 0);
            }
            if (valid) {
                const int c2 = loc*16 + l15, h2 = c2 / 20, dloc = c2 % 20;
                unsigned short* qs  = uS + h2*1024;
                unsigned short* ks_ = uS + (4+h2)*1024;
                unsigned short* vs  = uS + (8+h2)*1024;
                #pragma unroll
                for (int r = 0; r < 4; ++r) {
                    int row0 = g*4 + r, row1 = 16 + row0;
                    unsigned short v0 = f2bf(c0[r]), v1 = f2bf(c1[r]);
                    if (m == 0)      { qs[row0*32 + dloc] = v0; qs[row1*32 + dloc] = v1; }
                    else if (m == 1) { ks_[row0*32 + dloc] = v0; ks_[row1*32 + dloc] = v1; }
                    else             { vs[dloc*32 + row0] = v0; vs[dloc*32 + row1] = v1; }
                }
            }
        }
        __syncthreads();

        // ---- attention + PV merged (wave w owns slice w) ----
        {
            unsigned short* qh = uS + w*1024;
            const unsigned short* kh = uS + (4+w)*1024;
            const unsigned short* vh = uS + (8+w)*1024;
            bh8 a0 = *(const bh8*)&qh[l15*32 + g*8];
            bh8 a1 = *(const bh8*)&qh[(16+l15)*32 + g*8];
            bh8 b0 = *(const bh8*)&kh[l15*32 + g*8];
            bh8 b1 = *(const bh8*)&kh[(16+l15)*32 + g*8];
            bh8 vb0 = *(const bh8*)&vh[l15*32 + g*8];
            bh8 vb1 = *(const bh8*)&vh[(16+l15)*32 + g*8];
            f32x4 s00 = {0.f,0.f,0.f,0.f}, s01 = {0.f,0.f,0.f,0.f};
            f32x4 s10 = {0.f,0.f,0.f,0.f}, s11 = {0.f,0.f,0.f,0.f};
            s00 = __builtin_amdgcn_mfma_f32_16x16x32_bf16(a0, b0, s00, 0, 0, 0);
            s01 = __builtin_amdgcn_mfma_f32_16x16x32_bf16(a0, b1, s01, 0, 0, 0);
            s10 = __builtin_amdgcn_mfma_f32_16x16x32_bf16(a1, b0, s10, 0, 0, 0);
            s11 = __builtin_amdgcn_mfma_f32_16x16x32_bf16(a1, b1, s11, 0, 0, 0);
            const float maskv = (l15 >= 14) ? -1e30f : 0.f;   // key cols >=30
            float sum0[4], sum1[4];
            #pragma unroll
            for (int r = 0; r < 4; ++r) {
                float ea0 = __expf(s00[r]*sc);
                float ea1 = __expf(s01[r]*sc + maskv);
                float eb0 = __expf(s10[r]*sc);
                float eb1 = __expf(s11[r]*sc + maskv);
                int row0 = g*4 + r, row1 = 16 + row0;
                qh[row0*32 + l15]      = f2bf(ea0);
                qh[row0*32 + 16 + l15] = f2bf(ea1);
                qh[row1*32 + l15]      = f2bf(eb0);
                qh[row1*32 + 16 + l15] = f2bf(eb1);
                sum0[r] = ea0 + ea1;
                sum1[r] = eb0 + eb1;
            }
            asm volatile("s_waitcnt lgkmcnt(0)" ::: "memory");
            __builtin_amdgcn_sched_barrier(0);

            bh8 pa0 = *(const bh8*)&qh[l15*32 + g*8];
            bh8 pa1 = *(const bh8*)&qh[(16+l15)*32 + g*8];
            f32x4 o00 = {0.f,0.f,0.f,0.f}, o01 = {0.f,0.f,0.f,0.f};
            f32x4 o10 = {0.f,0.f,0.f,0.f}, o11 = {0.f,0.f,0.f,0.f};
            o00 = __builtin_amdgcn_mfma_f32_16x16x32_bf16(pa0, vb0, o00, 0, 0, 0);
            o01 = __builtin_amdgcn_mfma_f32_16x16x32_bf16(pa0, vb1, o01, 0, 0, 0);
            o10 = __builtin_amdgcn_mfma_f32_16x16x32_bf16(pa1, vb0, o10, 0, 0, 0);
            o11 = __builtin_amdgcn_mfma_f32_16x16x32_bf16(pa1, vb1, o11, 0, 0, 0);
            float inv0[4], inv1[4];
            #pragma unroll
            for (int r = 0; r < 4; ++r) {
                float t0 = sum0[r], t1 = sum1[r];
                #pragma unroll
                for (int mk = 1; mk < 16; mk <<= 1) {
                    t0 += __shfl_xor(t0, mk);
                    t1 += __shfl_xor(t1, mk);
                }
                inv0[r] = 1.f / t0;
                inv1[r] = 1.f / t1;
            }
            const int base = (hg*4 + w) * 20;
            #pragma unroll
            for (int r = 0; r < 4; ++r) {
                int row0 = g*4 + r, row1 = 16 + g*4 + r;
                outS[row0*408 + base + l15] = f2bf(o00[r] * inv0[r]);
                if (l15 < 4) outS[row0*408 + base + 16 + l15] = f2bf(o01[r] * inv0[r]);
                outS[row1*408 + base + l15] = f2bf(o10[r] * inv1[r]);
                if (l15 < 4) outS[row1*408 + base + 16 + l15] = f2bf(o11[r] * inv1[r]);
            }
        }
        __syncthreads();
    }

    // ---- pooling scores via MFMA: tanh(out@wp) @ qp; half-batched B ----
    for (int i = tid; i < 32*16; i += 256) poolP[i] = 0.f;
    __syncthreads();
    for (int t = w; t < 13; t += 4) {
        const unsigned short* wb = wpT + (size_t)(t*16 + l15) * 416;
        f32x4 c0 = {0.f,0.f,0.f,0.f}, c1 = {0.f,0.f,0.f,0.f};
        bh8 bfr[7];
        #pragma unroll
        for (int ks = 0; ks < 7; ++ks)
            bfr[ks] = *(const bh8*)&wb[ks*32 + g*8];
        __builtin_amdgcn_sched_barrier(0);
        #pragma unroll
        for (int ks = 0; ks < 7; ++ks) {
            bh8 a0 = *(const bh8*)&outS[l15*408 + ks*32 + g*8];
            bh8 a1 = *(const bh8*)&outS[(16+l15)*408 + ks*32 + g*8];
            c0 = __builtin_amdgcn_mfma_f32_16x16x32_bf16(a0, bfr[ks], c0, 0, 0, 0);
            c1 = __builtin_amdgcn_mfma_f32_16x16x32_bf16(a1, bfr[ks], c1, 0, 0, 0);
        }
        __builtin_amdgcn_sched_barrier(0);
        #pragma unroll
        for (int ks = 0; ks < 6; ++ks)
            bfr[ks] = *(const bh8*)&wb[(7+ks)*32 + g*8];
        __builtin_amdgcn_sched_barrier(0);
        #pragma unroll
        for (int ks = 0; ks < 6; ++ks) {
            bh8 a0 = *(const bh8*)&outS[l15*408 + (7+ks)*32 + g*8];
            bh8 a1 = *(const bh8*)&outS[(16+l15)*408 + (7+ks)*32 + g*8];
            c0 = __builtin_amdgcn_mfma_f32_16x16x32_bf16(a0, bfr[ks], c0, 0, 0, 0);
            c1 = __builtin_amdgcn_mfma_f32_16x16x32_bf16(a1, bfr[ks], c1, 0, 0, 0);
        }
        int n = t*16 + l15;
        float qpn = (n < PP) ? qp[n] : 0.f;
        #pragma unroll
        for (int r = 0; r < 4; ++r) {
            float v0 = tanhf(c0[r]) * qpn;
            float v1 = tanhf(c1[r]) * qpn;
            #pragma unroll
            for (int mk = 1; mk < 16; mk <<= 1) {
                v0 += __shfl_xor(v0, mk);
                v1 += __shfl_xor(v1, mk);
            }
            if (l15 == 0) {
                poolP[(g*4+r)*16 + t]    = v0;
                poolP[(16+g*4+r)*16 + t] = v1;
            }
        }
    }
    __syncthreads();

    if (tid < 64) {
        float s = -1e30f;
        if (tid < TITLE) {
            s = 0.f;
            for (int t = 0; t < 13; ++t) s += poolP[tid*16 + t];
        }
        float mx = s;
        #pragma unroll
        for (int mk = 1; mk < 64; mk <<= 1) mx = fmaxf(mx, __shfl_xor(mx, mk));
        float e = (tid < TITLE) ? __expf(s - mx) : 0.f;
        float ssum = e;
        #pragma unroll
        for (int mk = 1; mk < 64; mk <<= 1) ssum += __shfl_xor(ssum, mk);
        if (tid < TITLE) alphaS[tid] = e / ssum;
    }
    __syncthreads();
    for (int dd = tid; dd < DD; dd += 256) {
        float a = 0.f;
        for (int t = 0; t < TITLE; ++t) a += alphaS[t] * bf2f(outS[t*408 + dd]);
        odst[dd] = a;
    }
}

// ---------------------------------------------------------------------------
// K2a: m = h @ W via MFMA; 16 rows x half-n per block, grid (625,2).
// r19: launch_bounds(256,4) — register-diet lever applied to tail (r18 find).
// ---------------------------------------------------------------------------
__global__ __launch_bounds__(256, 4) void mm_nodes_mfma(
    const float* __restrict__ A, const unsigned short* __restrict__ WT,
    unsigned short* __restrict__ Mo)
{
    __shared__ __align__(16) unsigned short aS[16 * 424];
    const int r0 = blockIdx.x * 16, ny = blockIdx.y, tid = threadIdx.x;
    const int w = tid >> 6, lane = tid & 63, g = lane >> 4, l15 = lane & 15;
    for (int i = tid; i < 16*424; i += 256) {
        int r = i / 424, c = i % 424;
        float v = (c < DD) ? A[(size_t)(r0 + r)*DD + c] : 0.f;
        aS[i] = f2bf(v);
    }
    __syncthreads();
    const int tstart = ny * 13, tcnt = ny ? 12 : 13;
    for (int tt = w; tt < tcnt; tt += 4) {
        int t = tstart + tt;
        const unsigned short* wb = WT + (size_t)(t*16 + l15) * 424;
        f32x4 c0 = {0.f,0.f,0.f,0.f};
        #pragma unroll
        for (int ks = 0; ks < 13; ++ks) {
            bh8 a0 = *(const bh8*)&aS[l15*424 + ks*32 + g*8];
            bh8 b  = *(const bh8*)&wb[ks*32 + g*8];
            c0 = __builtin_amdgcn_mfma_f32_16x16x32_bf16(a0, b, c0, 0, 0, 0);
        }
        int d = t*16 + l15;
        #pragma unroll
        for (int r = 0; r < 4; ++r)
            Mo[(size_t)(r0 + g*4 + r)*DD + d] = f2bf(c0[r]);
    }
}

// ---------------------------------------------------------------------------
// CSR build: count -> exclusive scan -> cursor scatter
// ---------------------------------------------------------------------------
__global__ __launch_bounds__(256) void count_edges(
    const int* __restrict__ ei, int* __restrict__ cnt)
{
    int e = blockIdx.x * 256 + threadIdx.x;
    if (e < EE) atomicAdd(&cnt[ei[EE + e]], 1);
}

__global__ __launch_bounds__(256) void build_offsets(
    const int* __restrict__ cnt, int* __restrict__ off, int* __restrict__ cursor)
{
    __shared__ int csum[256];
    const int tid = threadIdx.x;
    const int chunk = (NN + 255) / 256;   // 40
    int s = 0;
    for (int i = 0; i < chunk; ++i) {
        int idx = tid * chunk + i;
        if (idx < NN) s += cnt[idx];
    }
    csum[tid] = s;
    __syncthreads();
    if (tid == 0) {
        int run = 0;
        for (int i = 0; i < 256; ++i) { int c = csum[i]; csum[i] = run; run += c; }
    }
    __syncthreads();
    int run = csum[tid];
    for (int i = 0; i < chunk; ++i) {
        int idx = tid * chunk + i;
        if (idx < NN) {
            off[idx] = run; cursor[idx] = run;
            run += cnt[idx];
        }
    }
}

__global__ __launch_bounds__(256) void fill_csr(
    const int* __restrict__ ei, int* __restrict__ cursor, int* __restrict__ srclist)
{
    int e = blockIdx.x * 256 + threadIdx.x;
    if (e < EE) {
        int d = ei[EE + e];
        int pos = atomicAdd(&cursor[d], 1);
        srclist[pos] = ei[e];
    }
}

// ---------------------------------------------------------------------------
// K2b: agg[node] = sum over incoming edges of m[src]  (m is bf16).
// dword loads (r17-proven); launch_bounds(256,4) for occupancy headroom.
// ---------------------------------------------------------------------------
__global__ __launch_bounds__(256, 4) void gather_agg(
    const unsigned short* __restrict__ m, const int* __restrict__ off,
    const int* __restrict__ cnt, const int* __restrict__ srclist,
    float* __restrict__ agg)
{
    __shared__ int sl[128];
    const int node = blockIdx.x, tid = threadIdx.x;
    const int o0 = off[node], deg = cnt[node];
    float acc0 = 0.f, acc1 = 0.f;
    const int d0 = 2*tid;               // active when tid < 200
    const bool act = (d0 < DD);
    for (int j0 = 0; j0 < deg; j0 += 128) {
        if (tid < 128 && j0 + tid < deg) sl[tid] = srclist[o0 + j0 + tid];
        __syncthreads();
        const int jn = (deg - j0 < 128) ? (deg - j0) : 128;
        if (act) {
            for (int j = 0; j < jn; ++j) {
                const unsigned int u =
                    *(const unsigned int*)&m[(size_t)sl[j] * DD + d0];
                acc0 += bf2f((unsigned short)(u & 0xffffu));
                acc1 += bf2f((unsigned short)(u >> 16));
            }
        }
        __syncthreads();
    }
    if (act) {
        agg[(size_t)node * DD + d0]     = acc0;
        agg[(size_t)node * DD + d0 + 1] = acc1;
    }
}

// ---------------------------------------------------------------------------
// K2c: GRU cell via MFMA; 16 rows x half-n per block, grid (625,2).
// r19: launch_bounds(256,3) — safe bound (24 acc regs + 8 load streams).
// ---------------------------------------------------------------------------
__global__ __launch_bounds__(256, 3) void gru_step_mfma(
    const float* __restrict__ agg, const float* __restrict__ hin,
    const unsigned short* __restrict__ wihT, const unsigned short* __restrict__ whhT,
    const float* __restrict__ bih, const float* __restrict__ bhh,
    float* __restrict__ hout)
{
    __shared__ __align__(16) unsigned short aggS[16 * 424];
    __shared__ __align__(16) unsigned short hS[16 * 424];
    const int r0 = blockIdx.x * 16, ny = blockIdx.y, tid = threadIdx.x;
    const int w = tid >> 6, lane = tid & 63, g = lane >> 4, l15 = lane & 15;
    for (int i = tid; i < 16*424; i += 256) {
        int r = i / 424, c = i % 424;
        float va = 0.f, vh = 0.f;
        if (c < DD) {
            va = agg[(size_t)(r0 + r)*DD + c];
            vh = hin[(size_t)(r0 + r)*DD + c];
        }
        aggS[i] = f2bf(va); hS[i] = f2bf(vh);
    }
    __syncthreads();
    const int tstart = ny * 13, tcnt = ny ? 12 : 13;
    for (int tt = w; tt < tcnt; tt += 4) {
        int t = tstart + tt;
        int d = t*16 + l15;
        const unsigned short* bri = wihT + (size_t)d * 424;
        const unsigned short* bzi = wihT + (size_t)(400 + d) * 424;
        const unsigned short* bni = wihT + (size_t)(800 + d) * 424;
        const unsigned short* brh = whhT + (size_t)d * 424;
        const unsigned short* bzh = whhT + (size_t)(400 + d) * 424;
        const unsigned short* bnh = whhT + (size_t)(800 + d) * 424;
        f32x4 ir = {0.f,0.f,0.f,0.f}, iz = {0.f,0.f,0.f,0.f}, in_ = {0.f,0.f,0.f,0.f};
        f32x4 hr = {0.f,0.f,0.f,0.f}, hz = {0.f,0.f,0.f,0.f}, hn = {0.f,0.f,0.f,0.f};
        #pragma unroll
        for (int ks = 0; ks < 13; ++ks) {
            bh8 aa = *(const bh8*)&aggS[l15*424 + ks*32 + g*8];
            bh8 ah = *(const bh8*)&hS[l15*424 + ks*32 + g*8];
            bh8 b0 = *(const bh8*)&bri[ks*32 + g*8];
            bh8 b1 = *(const bh8*)&bzi[ks*32 + g*8];
            bh8 b2 = *(const bh8*)&bni[ks*32 + g*8];
            bh8 b3 = *(const bh8*)&brh[ks*32 + g*8];
            bh8 b4 = *(const bh8*)&bzh[ks*32 + g*8];
            bh8 b5 = *(const bh8*)&bnh[ks*32 + g*8];
            ir  = __builtin_amdgcn_mfma_f32_16x16x32_bf16(aa, b0, ir,  0, 0, 0);
            iz  = __builtin_amdgcn_mfma_f32_16x16x32_bf16(aa, b1, iz,  0, 0, 0);
            in_ = __builtin_amdgcn_mfma_f32_16x16x32_bf16(aa, b2, in_, 0, 0, 0);
            hr  = __builtin_amdgcn_mfma_f32_16x16x32_bf16(ah, b3, hr,  0, 0, 0);
            hz  = __builtin_amdgcn_mfma_f32_16x16x32_bf16(ah, b4, hz,  0, 0, 0);
            hn  = __builtin_amdgcn_mfma_f32_16x16x32_bf16(ah, b5, hn,  0, 0, 0);
        }
        float bir = bih[d], biz = bih[400+d], bin = bih[800+d];
        float bhr = bhh[d], bhz = bhh[400+d], bhn = bhh[800+d];
        #pragma unroll
        for (int r = 0; r < 4; ++r) {
            int grow = r0 + g*4 + r;
            float hl = hin[(size_t)grow*DD + d];
            float rg = 1.f/(1.f + __expf(-(ir[r]+bir + hr[r]+bhr)));
            float zg = 1.f/(1.f + __expf(-(iz[r]+biz + hz[r]+bhz)));
            float ng = tanhf(in_[r]+bin + rg*(hn[r]+bhn));
            hout[(size_t)grow*DD + d] = (1.f-zg)*ng + zg*hl;
        }
    }
}

// ---------------------------------------------------------------------------
// K3a: clicked_total = concat(x_enc[midx], h[midx])*mask @ w_click + b_click
// r19: launch_bounds(256,4).
// ---------------------------------------------------------------------------
__global__ __launch_bounds__(256, 4) void clicked_mm(
    const int* __restrict__ map, const float* __restrict__ xe,
    const float* __restrict__ hg, const float* __restrict__ wc,
    const float* __restrict__ bc, float* __restrict__ ct)
{
    __shared__ float a[8][2*DD];
    const int r0 = blockIdx.x * 8, tid = threadIdx.x;
    for (int i = tid; i < 8*2*DD; i += 256) {
        int r = i/(2*DD), k = i%(2*DD);
        int mi = map[r0 + r];
        float v = 0.f;
        if (mi >= 0) v = (k < DD) ? xe[(size_t)mi*DD + k] : hg[(size_t)mi*DD + (k-DD)];
        a[r][k] = v;
    }
    __syncthreads();
    for (int d = tid; d < DD; d += 256) {
        float acc[8] = {0,0,0,0,0,0,0,0};
        for (int k = 0; k < 2*DD; ++k) {
            float w = wc[(size_t)k*DD + d];
            #pragma unroll
            for (int r = 0; r < 8; ++r) acc[r] += a[r][k]*w;
        }
        float bb = bc[d];
        #pragma unroll
        for (int r = 0; r < 8; ++r) ct[(size_t)(r0+r)*DD + d] = acc[r] + bb;
    }
}

// ---------------------------------------------------------------------------
// K3b: uq/uk/uv = ct @ u_wq/u_wk/u_wv.  r19: launch_bounds(256,4).
// ---------------------------------------------------------------------------
__global__ __launch_bounds__(256, 4) void user_qkv(
    const float* __restrict__ ct,
    const float* __restrict__ wq, const float* __restrict__ wk, const float* __restrict__ wv,
    float* __restrict__ uq, float* __restrict__ uk, float* __restrict__ uv)
{
    __shared__ float a[8][DD];
    const int r0 = blockIdx.x * 8, tid = threadIdx.x;
    for (int i = tid; i < 8*DD; i += 256)
        a[i/DD][i%DD] = ct[(size_t)(r0 + i/DD)*DD + i%DD];
    __syncthreads();
    for (int d = tid; d < DD; d += 256) {
        float aq[8]={0,0,0,0,0,0,0,0}, ak[8]={0,0,0,0,0,0,0,0}, av[8]={0,0,0,0,0,0,0,0};
        for (int k = 0; k < DD; ++k) {
            float wq_ = wq[(size_t)k*DD + d];
            float wk_ = wk[(size_t)k*DD + d];
            float wv_ = wv[(size_t)k*DD + d];
            #pragma unroll
            for (int r = 0; r < 8; ++r) {
                float x = a[r][k];
                aq[r] += x*wq_; ak[r] += x*wk_; av[r] += x*wv_;
            }
        }
        #pragma unroll
        for (int r = 0; r < 8; ++r) {
            uq[(size_t)(r0+r)*DD + d] = aq[r];
            uk[(size_t)(r0+r)*DD + d] = ak[r];
            uv[(size_t)(r0+r)*DD + d] = av[r];
        }
    }
}

// ---------------------------------------------------------------------------
// K3c: masked MHSA per (batch, head); block = 64 threads
// ---------------------------------------------------------------------------
__global__ __launch_bounds__(64) void user_attn(
    const float* __restrict__ uq, const float* __restrict__ uk,
    const float* __restrict__ uv, const int* __restrict__ map,
    float* __restrict__ uo)
{
    const int b = blockIdx.x / HH, h = blockIdx.x % HH, tid = threadIdx.x;
    __shared__ float q[NCK][DHD], k[NCK][DHD], v[NCK][DHD];
    __shared__ float sc[NCK][NCK+2];
    __shared__ float biasl[NCK];
    for (int i = tid; i < NCK*DHD; i += 64) {
        int c = i/DHD, d = i%DHD;
        size_t base = ((size_t)b*NCK + c)*DD + h*DHD + d;
        q[c][d] = uq[base]; k[c][d] = uk[base]; v[c][d] = uv[base];
    }
    for (int i = tid; i < NCK; i += 64)
        biasl[i] = (map[b*NCK + i] >= 0) ? 0.f : -1e9f;
    __syncthreads();
    for (int i = tid; i < NCK*NCK; i += 64) {
        int t = i/NCK, k2 = i%NCK;
        float s = 0.f;
        #pragma unroll
        for (int d4 = 0; d4 < 5; ++d4) {
            const float4 qa = *(const float4*)&q[t][d4*4];
            const float4 kb = *(const float4*)&k[k2][d4*4];
            s += qa.x*kb.x + qa.y*kb.y + qa.z*kb.z + qa.w*kb.w;
        }
        sc[t][k2] = s * 0.2236067977f + biasl[k2];
    }
    __syncthreads();
    if (tid < NCK) {
        float mx = -1e30f;
        for (int k2 = 0; k2 < NCK; ++k2) mx = fmaxf(mx, sc[tid][k2]);
        float ssum = 0.f;
        for (int k2 = 0; k2 < NCK; ++k2) { float e = __expf(sc[tid][k2]-mx); sc[tid][k2] = e; ssum += e; }
        float inv = 1.f/ssum;
        for (int k2 = 0; k2 < NCK; ++k2) sc[tid][k2] *= inv;
    }
    __syncthreads();
    for (int i = tid; i < NCK*DHD; i += 64) {
        int t = i/DHD, d = i%DHD;
        float o = 0.f;
        for (int k2 = 0; k2 < NCK; ++k2) o += sc[t][k2]*v[k2][d];
        uo[((size_t)b*NCK + t)*DD + h*DHD + d] = o;
    }
}

// ---------------------------------------------------------------------------
// K3d-1: pool scores via MFMA: alphaRaw[row] = tanh(uo[row]@uwp) @ uqp
// r19: launch_bounds(256,4).
// ---------------------------------------------------------------------------
__global__ __launch_bounds__(256, 4) void pool_scores_mfma(
    const float* __restrict__ uo, const unsigned short* __restrict__ uwpT,
    const float* __restrict__ uqp, float* __restrict__ alphaRaw)
{
    __shared__ __align__(16) unsigned short aS[16 * 424];
    __shared__ float poolB[16][16];
    const int r0 = blockIdx.x * 16, tid = threadIdx.x;
    const int w = tid >> 6, lane = tid & 63, g = lane >> 4, l15 = lane & 15;
    for (int i = tid; i < 16*424; i += 256) {
        int r = i / 424, c = i % 424;
        float v = (c < DD) ? uo[(size_t)(r0 + r)*DD + c] : 0.f;
        aS[i] = f2bf(v);
    }
    if (tid < 256) poolB[tid/16][tid%16] = 0.f;
    __syncthreads();
    for (int t = w; t < 13; t += 4) {
        const unsigned short* wb = uwpT + (size_t)(t*16 + l15) * 416;
        bh8 bfr[13];
        #pragma unroll
        for (int ks = 0; ks < 13; ++ks)
            bfr[ks] = *(const bh8*)&wb[ks*32 + g*8];
        __builtin_amdgcn_sched_barrier(0);
        f32x4 c0 = {0.f,0.f,0.f,0.f};
        #pragma unroll
        for (int ks = 0; ks < 13; ++ks) {
            bh8 a0 = *(const bh8*)&aS[l15*424 + ks*32 + g*8];
            c0 = __builtin_amdgcn_mfma_f32_16x16x32_bf16(a0, bfr[ks], c0, 0, 0, 0);
        }
        int n = t*16 + l15;
        float qpn = (n < PP) ? uqp[n] : 0.f;
        #pragma unroll
        for (int r = 0; r < 4; ++r) {
            float v = tanhf(c0[r]) * qpn;
            #pragma unroll
            for (int mk = 1; mk < 16; mk <<= 1) v += __shfl_xor(v, mk);
            if (l15 == 0) poolB[g*4 + r][t] = v;
        }
    }
    __syncthreads();
    if (tid < 16) {
        float s = 0.f;
        for (int t = 0; t < 13; ++t) s += poolB[tid][t];
        alphaRaw[r0 + tid] = s;
    }
}

// ---------------------------------------------------------------------------
// K3d-2: masked softmax over alphaRaw + weighted sum -> user_emb
// ---------------------------------------------------------------------------
__global__ __launch_bounds__(256) void user_finalize(
    const float* __restrict__ alphaRaw, const int* __restrict__ map,
    const float* __restrict__ uo, float* __restrict__ user_emb)
{
    const int b = blockIdx.x, tid = threadIdx.x;
    __shared__ float alpha[64];
    if (tid < 64) {
        float a = -1e30f;
        if (tid < NCK)
            a = alphaRaw[b*NCK + tid] + ((map[b*NCK + tid] >= 0) ? 0.f : -1e9f);
        float mx = a;
        #pragma unroll
        for (int mk = 1; mk < 64; mk <<= 1) mx = fmaxf(mx, __shfl_xor(mx, mk));
        float e = (tid < NCK) ? __expf(a - mx) : 0.f;
        float ssum = e;
        #pragma unroll
        for (int mk = 1; mk < 64; mk <<= 1) ssum += __shfl_xor(ssum, mk);
        if (tid < NCK) alpha[tid] = e / ssum;
    }
    __syncthreads();
    for (int d = tid; d < DD; d += 256) {
        float acc = 0.f;
        for (int t = 0; t < NCK; ++t) acc += alpha[t] * uo[((size_t)b*NCK + t)*DD + d];
        user_emb[(size_t)b*DD + d] = acc;
    }
}

// ---------------------------------------------------------------------------
// K5: candidate scoring + NCE loss; single block
// ---------------------------------------------------------------------------
__global__ __launch_bounds__(256) void score_loss(
    const float* __restrict__ cr, const float* __restrict__ cf,
    const float* __restrict__ ue, const int* __restrict__ label,
    float* __restrict__ dout)
{
    __shared__ float sr[BB][NCAND], sf[BB][NCAND], red[BB];
    const int tid = threadIdx.x;
    for (int i = tid; i < 2*BB*NCAND; i += 256) {
        int which = i / (BB*NCAND);
        int r = i % (BB*NCAND);
        int b = r / NCAND, c = r % NCAND;
        const float* ce = (which ? cf : cr) + (size_t)r*DD;
        const float* u = ue + (size_t)b*DD;
        float s = 0.f;
        for (int d = 0; d < DD; ++d) s += ce[d]*u[d];
        if (which) sf[b][c] = s; else sr[b][c] = s;
        dout[1 + i] = s;
    }
    __syncthreads();
    if (tid < BB) {
        int b = tid;
        float mr = -1e30f, mf = -1e30f;
        for (int c = 0; c < NCAND; ++c) { mr = fmaxf(mr, sr[b][c]); mf = fmaxf(mf, sf[b][c]); }
        float er = 0.f, ef = 0.f;
        for (int c = 0; c < NCAND; ++c) { er += expf(sr[b][c]-mr); ef += expf(sf[b][c]-mf); }
        float lser = logf(er)+mr, lsef = logf(ef)+mf;
        int lab = label[b]; lab = lab < 0 ? 0 : (lab > NCAND-1 ? NCAND-1 : lab);
        float crb = lser - sr[b][lab];
        float cfb = 0.f;
        for (int c = 0; c < NCAND; ++c) cfb += (lsef - sf[b][c]);
        red[tid] = crb + 0.5f * (cfb / (float)NCAND);
    }
    __syncthreads();
    if (tid == 0) {
        float L = 0.f;
        for (int b = 0; b < BB; ++b) L += red[b];
        dout[0] = L / (float)BB;
    }
}

// ---------------------------------------------------------------------------
extern "C" void kernel_launch(void* const* d_in, const int* in_sizes, int n_in,
                              void* d_out, int out_size, void* d_ws, size_t ws_size,
                              hipStream_t stream) {
    (void)in_sizes; (void)n_in; (void)out_size; (void)ws_size;
    const int*   sub_x  = (const int*)d_in[0];
    const int*   edge   = (const int*)d_in[1];
    const int*   mapi   = (const int*)d_in[2];
    const int*   cand   = (const int*)d_in[3];
    const int*   fcand  = (const int*)d_in[4];
    const int*   label  = (const int*)d_in[5];
    const float* glove  = (const float*)d_in[6];
    const float* nwq    = (const float*)d_in[7];
    const float* nwk    = (const float*)d_in[8];
    const float* nwv    = (const float*)d_in[9];
    const float* nwp    = (const float*)d_in[10];
    const float* nqp    = (const float*)d_in[11];
    const float* ggc    = (const float*)d_in[12];
    const float* wih    = (const float*)d_in[13];
    const float* whh    = (const float*)d_in[14];
    const float* bih    = (const float*)d_in[15];
    const float* bhh    = (const float*)d_in[16];
    const float* wclick = (const float*)d_in[17];
    const float* bclick = (const float*)d_in[18];
    const float* uwq    = (const float*)d_in[19];
    const float* uwk    = (const float*)d_in[20];
    const float* uwv    = (const float*)d_in[21];
    const float* uwp    = (const float*)d_in[22];
    const float* uqp    = (const float*)d_in[23];

    // workspace layout (floats); ws_size = 256 MiB
    float* ws     = (float*)d_ws;
    float* x_enc  = ws;                       // 4,000,000 f
    float* hbuf   = ws + 4000000;             // 4,000,000 f
    float* region = ws + 8000000;             // 8,000,000 f shared region
    unsigned short* mbufBF = (unsigned short*)region;   // GGC: m bf16 [NN][400]
    float* aggbuf = region + 4000000;         // GGC: agg f32
    // after GGC, region reused:
    float* ct   = region;                     // 1,280,000
    float* uq   = region + 1280000;
    float* uk   = region + 2560000;
    float* uv   = region + 3840000;
    float* uo   = region + 5120000;           // 1,280,000
    float* user = region + 6400000;           // 25,600
    float* alphaRaw = region + 6430000;       // 3,200
    // int area at byte offset 64 MB
    int* ibase   = (int*)((char*)d_ws + (size_t)64*1024*1024);
    int* cnt     = ibase;                     // 10,000
    int* off     = ibase + 10000;             // 10,000
    int* cursor  = ibase + 20000;             // 10,000
    int* srclist = ibase + 30000;             // 200,000
    // bf16 prepped weights
    unsigned short* Wt   = (unsigned short*)(ws + 17100000);  // 1200*320 sh
    unsigned short* wpT  = (unsigned short*)(ws + 17300000);  // 208*416 sh
    unsigned short* wggT = (unsigned short*)(ws + 17400000);  // 3*400*424 sh
    unsigned short* wihT = (unsigned short*)(ws + 17700000);  // 1200*424 sh
    unsigned short* whhT = (unsigned short*)(ws + 18000000);  // 1200*424 sh
    unsigned short* uwpT = (unsigned short*)(ws + 18300000);  // 208*416 sh
    float* hbuf2 = ws + 19000000;             // 4,000,000 f (GRU ping-pong)
    float* crnc  = ws + 23500000;             // 128,000 f
    float* cfnc  = ws + 23700000;             // 128,000 f

    // 0) prep transposed bf16 weights (tiny; L2-resident afterwards)
    prep_wt<<<1500, 256, 0, stream>>>(nwq, nwk, nwv, Wt);
    prep_wpt<<<338, 256, 0, stream>>>(nwp, wpT);
    prep_wpt<<<338, 256, 0, stream>>>(uwp, uwpT);
    prep_wgg<<<(3*400*424 + 255)/256, 256, 0, stream>>>(ggc, wggT);
    prep_gruw<<<(1200*424 + 255)/256, 256, 0, stream>>>(wih, whh, wihT, whhT);

    // 1) encode all nodes + candidates (one fused launch; r18-proven)
    news_enc<<<NN + 2*BB*NCAND, 256, 0, stream>>>(
        sub_x, cand, fcand, glove, Wt, wpT, nqp, x_enc, crnc, cfnc);

    // 1b) build CSR-by-destination once
    hipMemsetAsync(cnt, 0, NN*sizeof(int), stream);
    count_edges<<<(EE+255)/256, 256, 0, stream>>>(edge, cnt);
    build_offsets<<<1, 256, 0, stream>>>(cnt, off, cursor);
    fill_csr<<<(EE+255)/256, 256, 0, stream>>>(edge, cursor, srclist);

    // 2) GatedGraphConv x3
    const float* hin = x_enc;
    float* houts[3] = {hbuf, hbuf2, hbuf};
    for (int l = 0; l < 3; ++l) {
        mm_nodes_mfma<<<dim3(625,2), 256, 0, stream>>>(hin, wggT + (size_t)l*400*424, mbufBF);
        gather_agg<<<NN, 256, 0, stream>>>(mbufBF, off, cnt, srclist, aggbuf);
        gru_step_mfma<<<dim3(625,2), 256, 0, stream>>>(aggbuf, hin, wihT, whhT, bih, bhh, houts[l]);
        hin = houts[l];
    }

    // 3) click + user encoder  (final h is in hbuf)
    clicked_mm<<<(BB*NCK)/8, 256, 0, stream>>>(mapi, x_enc, hbuf, wclick, bclick, ct);
    user_qkv<<<(BB*NCK)/8, 256, 0, stream>>>(ct, uwq, uwk, uwv, uq, uk, uv);
    user_attn<<<BB*HH, 64, 0, stream>>>(uq, uk, uv, mapi, uo);
    pool_scores_mfma<<<(BB*NCK)/16, 256, 0, stream>>>(uo, uwpT, uqp, alphaRaw);
    user_finalize<<<BB, 256, 0, stream>>>(alphaRaw, mapi, uo, user);

    // 4) scores + loss
    score_loss<<<1, 256, 0, stream>>>(crnc, cfnc, user, label, (float*)d_out);
}

// Round 20
// 2198.365 us; speedup vs baseline: 1.0219x; 1.0219x over previous
//
#include <hip/hip_runtime.h>
#include <cmath>

#define NN 10000
#define EE 200000
#define BB 64
#define NCK 50
#define NCAND 5
#define TOKS 38
#define TITLE 30
#define GDIM 300
#define HH 20
#define DHD 20
#define DD 400
#define PP 200

typedef __attribute__((ext_vector_type(8))) short bh8;
typedef __attribute__((ext_vector_type(4))) float f32x4;

__device__ __forceinline__ float bf2f(unsigned short u) {
    return __uint_as_float(((unsigned int)u) << 16);
}
__device__ __forceinline__ unsigned short f2bf(float f) {
    unsigned int u = __float_as_uint(f);
    u += 0x7fffu + ((u >> 16) & 1u);
    return (unsigned short)(u >> 16);
}

// ---------------------------------------------------------------------------
// prep: Wt[1200][320] bf16 = concat(wq,wk,wv) transposed, k-padded with zeros
// ---------------------------------------------------------------------------
__global__ __launch_bounds__(256) void prep_wt(
    const float* __restrict__ wq, const float* __restrict__ wk,
    const float* __restrict__ wv, unsigned short* __restrict__ Wt)
{
    int i = blockIdx.x * 256 + threadIdx.x;
    if (i >= 1200 * 320) return;
    int n = i / 320, k = i % 320;
    int m = n / 400, nn = n % 400;
    const float* W = (m == 0) ? wq : ((m == 1) ? wk : wv);
    float v = (k < GDIM) ? W[(size_t)k * DD + nn] : 0.f;
    Wt[i] = f2bf(v);
}

// prep: [208][416] bf16 = [400][200] f32 transposed, padded (wp / uwp)
__global__ __launch_bounds__(256) void prep_wpt(
    const float* __restrict__ wp, unsigned short* __restrict__ wpT)
{
    int i = blockIdx.x * 256 + threadIdx.x;
    if (i >= 208 * 416) return;
    int n = i / 416, k = i % 416;
    float v = (n < PP && k < DD) ? wp[(size_t)k * PP + n] : 0.f;
    wpT[i] = f2bf(v);
}

// prep: wggT[3][400][424] bf16 = ggc_w[l] transposed, k-padded
__global__ __launch_bounds__(256) void prep_wgg(
    const float* __restrict__ ggc, unsigned short* __restrict__ wggT)
{
    int i = blockIdx.x * 256 + threadIdx.x;
    if (i >= 3 * 400 * 424) return;
    int l = i / (400*424), rem = i % (400*424);
    int n = rem / 424, k = rem % 424;
    float v = (k < DD) ? ggc[(size_t)l*DD*DD + (size_t)k*DD + n] : 0.f;
    wggT[i] = f2bf(v);
}

// prep: wihT/whhT [1200][424] bf16 transposed, k-padded
__global__ __launch_bounds__(256) void prep_gruw(
    const float* __restrict__ wih, const float* __restrict__ whh,
    unsigned short* __restrict__ wihT, unsigned short* __restrict__ whhT)
{
    int i = blockIdx.x * 256 + threadIdx.x;
    if (i >= 1200 * 424) return;
    int n = i / 424, k = i % 424;
    wihT[i] = f2bf((k < DD) ? wih[(size_t)k*1200 + n] : 0.f);
    whhT[i] = f2bf((k < DD) ? whh[(size_t)k*1200 + n] : 0.f);
}

// ---------------------------------------------------------------------------
// K1: fused news encoder (nodes + real + fake candidates, one grid).
// r18-PROVEN FINAL: register diet (afr 80 + ba[5] 40 + acc 8 ~ 150 live) +
// __launch_bounds__(256,3) -> 3 waves/SIMD (LDS-bound cap), occupancy 35%,
// 1223 us. Unified VGPR+AGPR allocation (invisible in CSV VGPR_Count) was
// the long-standing occupancy cap.
// ---------------------------------------------------------------------------
__global__ __launch_bounds__(256, 3) void news_enc(
    const int* __restrict__ sub_x,
    const int* __restrict__ cand,
    const int* __restrict__ fcand,
    const float* __restrict__ glove,
    const unsigned short* __restrict__ Wt,     // [1200][320] bf16
    const unsigned short* __restrict__ wpT,    // [208][416] bf16
    const float* __restrict__ qp,
    float* __restrict__ x_enc,
    float* __restrict__ crnc,
    float* __restrict__ cfnc)
{
    __shared__ __align__(16) unsigned short uS[12288];         // 24576B
    __shared__ __align__(16) unsigned short outS[32*408 + 16]; // 26144B
    __shared__ int   tokS[32];
    __shared__ float alphaS[32];

    float* poolP = (float*)uS;   // valid after scr is dead

    const int tid  = threadIdx.x;
    const int item = blockIdx.x;
    const int w    = tid >> 6;        // wave 0..3
    const int lane = tid & 63;
    const int g    = lane >> 4;       // k-group 0..3
    const int l15  = lane & 15;

    const int* tsrc; float* odst;
    if (item < NN) {
        tsrc = sub_x + (size_t)item * TOKS;
        odst = x_enc + (size_t)item * DD;
    } else if (item < NN + BB*NCAND) {
        int li = item - NN;
        tsrc = cand + (size_t)li * TOKS;
        odst = crnc + (size_t)li * DD;
    } else {
        int li = item - NN - BB*NCAND;
        tsrc = fcand + (size_t)li * TOKS;
        odst = cfnc + (size_t)li * DD;
    }

    if (tid < TITLE) tokS[tid] = tsrc[tid];
    for (int i = tid; i < 12288/2; i += 256) ((unsigned int*)uS)[i] = 0u;
    for (int i = tid; i < (32*408+16)/2; i += 256) ((unsigned int*)outS)[i] = 0u;
    __syncthreads();

    // gather glove rows -> embS region of uS (rows 0..29, stride 328)
    for (int i = tid; i < TITLE * 75; i += 256) {
        int t = i / 75, g4 = i % 75;
        const float4 v = *(const float4*)&glove[(size_t)tokS[t] * GDIM + g4 * 4];
        uS[t*328 + g4*4+0] = f2bf(v.x);
        uS[t*328 + g4*4+1] = f2bf(v.y);
        uS[t*328 + g4*4+2] = f2bf(v.z);
        uS[t*328 + g4*4+3] = f2bf(v.w);
    }
    __syncthreads();

    // preload A-fragments into registers (80 VGPR); rows 30/31 are zero
    bh8 afr[2][10];
    #pragma unroll
    for (int mt = 0; mt < 2; ++mt)
        #pragma unroll
        for (int ks = 0; ks < 10; ++ks)
            afr[mt][ks] = *(const bh8*)&uS[(mt*16 + l15)*328 + ks*32 + g*8];
    __syncthreads();

    // re-zero uS: scr slices must start all-zero (NaN rule, r8 lesson)
    for (int i = tid; i < 12288/2; i += 256) ((unsigned int*)uS)[i] = 0u;
    __syncthreads();

    const float sc = 0.2236067977f;

    for (int hg = 0; hg < 5; ++hg) {
        // re-zero own q-slice pad cols 20..31 (P from previous hg wrote them)
        {
            unsigned short* qme = uS + w*1024;
            for (int i = lane; i < 32*6; i += 64) {
                int r = i / 6, c = 20 + (i % 6) * 2;
                *(unsigned int*)&qme[r*32 + c] = 0u;
            }
        }

        // ---- QKV: 15 n-tiles over 4 waves; ba[5] half-batched B-loads ----
        #pragma unroll
        for (int tt = 0; tt < 4; ++tt) {
            const int t = w*4 + tt;
            const bool valid = (t < 15);
            const int tc = valid ? t : 0;
            const int m = tc / 5, loc = tc % 5;
            const unsigned short* wb =
                Wt + (size_t)(m*400 + hg*80 + loc*16 + l15) * 320;
            f32x4 c0 = {0.f,0.f,0.f,0.f}, c1 = {0.f,0.f,0.f,0.f};
            bh8 ba[5];
            #pragma unroll
            for (int ks = 0; ks < 5; ++ks)
                ba[ks] = *(const bh8*)&wb[ks*32 + g*8];
            __builtin_amdgcn_sched_barrier(0);   // batch 1 pinned above
            #pragma unroll
            for (int ks = 0; ks < 5; ++ks) {
                c0 = __builtin_amdgcn_mfma_f32_16x16x32_bf16(afr[0][ks], ba[ks], c0, 0, 0, 0);
                c1 = __builtin_amdgcn_mfma_f32_16x16x32_bf16(afr[1][ks], ba[ks], c1, 0, 0, 0);
            }
            __builtin_amdgcn_sched_barrier(0);   // keep ba[] single-buffered
            #pragma unroll
            for (int ks = 0; ks < 5; ++ks)
                ba[ks] = *(const bh8*)&wb[(5+ks)*32 + g*8];
            __builtin_amdgcn_sched_barrier(0);   // batch 2 pinned above
            #pragma unroll
            for (int ks = 0; ks < 5; ++ks) {
                c0 = __builtin_amdgcn_mfma_f32_16x16x32_bf16(afr[0][5+ks], ba[ks], c0, 0, 0, 0);
                c1 = __builtin_amdgcn_mfma_f32_16x16x32_bf16(afr[1][5+ks], ba[ks], c1, 0, 0, 0);
            }
            if (valid) {
                const int c2 = loc*16 + l15, h2 = c2 / 20, dloc = c2 % 20;
                unsigned short* qs  = uS + h2*1024;
                unsigned short* ks_ = uS + (4+h2)*1024;
                unsigned short* vs  = uS + (8+h2)*1024;
                #pragma unroll
                for (int r = 0; r < 4; ++r) {
                    int row0 = g*4 + r, row1 = 16 + row0;
                    unsigned short v0 = f2bf(c0[r]), v1 = f2bf(c1[r]);
                    if (m == 0)      { qs[row0*32 + dloc] = v0; qs[row1*32 + dloc] = v1; }
                    else if (m == 1) { ks_[row0*32 + dloc] = v0; ks_[row1*32 + dloc] = v1; }
                    else             { vs[dloc*32 + row0] = v0; vs[dloc*32 + row1] = v1; }
                }
            }
        }
        __syncthreads();

        // ---- attention + PV merged (wave w owns slice w) ----
        {
            unsigned short* qh = uS + w*1024;
            const unsigned short* kh = uS + (4+w)*1024;
            const unsigned short* vh = uS + (8+w)*1024;
            bh8 a0 = *(const bh8*)&qh[l15*32 + g*8];
            bh8 a1 = *(const bh8*)&qh[(16+l15)*32 + g*8];
            bh8 b0 = *(const bh8*)&kh[l15*32 + g*8];
            bh8 b1 = *(const bh8*)&kh[(16+l15)*32 + g*8];
            bh8 vb0 = *(const bh8*)&vh[l15*32 + g*8];
            bh8 vb1 = *(const bh8*)&vh[(16+l15)*32 + g*8];
            f32x4 s00 = {0.f,0.f,0.f,0.f}, s01 = {0.f,0.f,0.f,0.f};
            f32x4 s10 = {0.f,0.f,0.f,0.f}, s11 = {0.f,0.f,0.f,0.f};
            s00 = __builtin_amdgcn_mfma_f32_16x16x32_bf16(a0, b0, s00, 0, 0, 0);
            s01 = __builtin_amdgcn_mfma_f32_16x16x32_bf16(a0, b1, s01, 0, 0, 0);
            s10 = __builtin_amdgcn_mfma_f32_16x16x32_bf16(a1, b0, s10, 0, 0, 0);
            s11 = __builtin_amdgcn_mfma_f32_16x16x32_bf16(a1, b1, s11, 0, 0, 0);
            const float maskv = (l15 >= 14) ? -1e30f : 0.f;   // key cols >=30
            float sum0[4], sum1[4];
            #pragma unroll
            for (int r = 0; r < 4; ++r) {
                float ea0 = __expf(s00[r]*sc);
                float ea1 = __expf(s01[r]*sc + maskv);
                float eb0 = __expf(s10[r]*sc);
                float eb1 = __expf(s11[r]*sc + maskv);
                int row0 = g*4 + r, row1 = 16 + row0;
                qh[row0*32 + l15]      = f2bf(ea0);
                qh[row0*32 + 16 + l15] = f2bf(ea1);
                qh[row1*32 + l15]      = f2bf(eb0);
                qh[row1*32 + 16 + l15] = f2bf(eb1);
                sum0[r] = ea0 + ea1;
                sum1[r] = eb0 + eb1;
            }
            asm volatile("s_waitcnt lgkmcnt(0)" ::: "memory");
            __builtin_amdgcn_sched_barrier(0);

            bh8 pa0 = *(const bh8*)&qh[l15*32 + g*8];
            bh8 pa1 = *(const bh8*)&qh[(16+l15)*32 + g*8];
            f32x4 o00 = {0.f,0.f,0.f,0.f}, o01 = {0.f,0.f,0.f,0.f};
            f32x4 o10 = {0.f,0.f,0.f,0.f}, o11 = {0.f,0.f,0.f,0.f};
            o00 = __builtin_amdgcn_mfma_f32_16x16x32_bf16(pa0, vb0, o00, 0, 0, 0);
            o01 = __builtin_amdgcn_mfma_f32_16x16x32_bf16(pa0, vb1, o01, 0, 0, 0);
            o10 = __builtin_amdgcn_mfma_f32_16x16x32_bf16(pa1, vb0, o10, 0, 0, 0);
            o11 = __builtin_amdgcn_mfma_f32_16x16x32_bf16(pa1, vb1, o11, 0, 0, 0);
            float inv0[4], inv1[4];
            #pragma unroll
            for (int r = 0; r < 4; ++r) {
                float t0 = sum0[r], t1 = sum1[r];
                #pragma unroll
                for (int mk = 1; mk < 16; mk <<= 1) {
                    t0 += __shfl_xor(t0, mk);
                    t1 += __shfl_xor(t1, mk);
                }
                inv0[r] = 1.f / t0;
                inv1[r] = 1.f / t1;
            }
            const int base = (hg*4 + w) * 20;
            #pragma unroll
            for (int r = 0; r < 4; ++r) {
                int row0 = g*4 + r, row1 = 16 + g*4 + r;
                outS[row0*408 + base + l15] = f2bf(o00[r] * inv0[r]);
                if (l15 < 4) outS[row0*408 + base + 16 + l15] = f2bf(o01[r] * inv0[r]);
                outS[row1*408 + base + l15] = f2bf(o10[r] * inv1[r]);
                if (l15 < 4) outS[row1*408 + base + 16 + l15] = f2bf(o11[r] * inv1[r]);
            }
        }
        __syncthreads();
    }

    // ---- pooling scores via MFMA: tanh(out@wp) @ qp; half-batched B ----
    for (int i = tid; i < 32*16; i += 256) poolP[i] = 0.f;
    __syncthreads();
    for (int t = w; t < 13; t += 4) {
        const unsigned short* wb = wpT + (size_t)(t*16 + l15) * 416;
        f32x4 c0 = {0.f,0.f,0.f,0.f}, c1 = {0.f,0.f,0.f,0.f};
        bh8 bfr[7];
        #pragma unroll
        for (int ks = 0; ks < 7; ++ks)
            bfr[ks] = *(const bh8*)&wb[ks*32 + g*8];
        __builtin_amdgcn_sched_barrier(0);
        #pragma unroll
        for (int ks = 0; ks < 7; ++ks) {
            bh8 a0 = *(const bh8*)&outS[l15*408 + ks*32 + g*8];
            bh8 a1 = *(const bh8*)&outS[(16+l15)*408 + ks*32 + g*8];
            c0 = __builtin_amdgcn_mfma_f32_16x16x32_bf16(a0, bfr[ks], c0, 0, 0, 0);
            c1 = __builtin_amdgcn_mfma_f32_16x16x32_bf16(a1, bfr[ks], c1, 0, 0, 0);
        }
        __builtin_amdgcn_sched_barrier(0);
        #pragma unroll
        for (int ks = 0; ks < 6; ++ks)
            bfr[ks] = *(const bh8*)&wb[(7+ks)*32 + g*8];
        __builtin_amdgcn_sched_barrier(0);
        #pragma unroll
        for (int ks = 0; ks < 6; ++ks) {
            bh8 a0 = *(const bh8*)&outS[l15*408 + (7+ks)*32 + g*8];
            bh8 a1 = *(const bh8*)&outS[(16+l15)*408 + (7+ks)*32 + g*8];
            c0 = __builtin_amdgcn_mfma_f32_16x16x32_bf16(a0, bfr[ks], c0, 0, 0, 0);
            c1 = __builtin_amdgcn_mfma_f32_16x16x32_bf16(a1, bfr[ks], c1, 0, 0, 0);
        }
        int n = t*16 + l15;
        float qpn = (n < PP) ? qp[n] : 0.f;
        #pragma unroll
        for (int r = 0; r < 4; ++r) {
            float v0 = tanhf(c0[r]) * qpn;
            float v1 = tanhf(c1[r]) * qpn;
            #pragma unroll
            for (int mk = 1; mk < 16; mk <<= 1) {
                v0 += __shfl_xor(v0, mk);
                v1 += __shfl_xor(v1, mk);
            }
            if (l15 == 0) {
                poolP[(g*4+r)*16 + t]    = v0;
                poolP[(16+g*4+r)*16 + t] = v1;
            }
        }
    }
    __syncthreads();

    if (tid < 64) {
        float s = -1e30f;
        if (tid < TITLE) {
            s = 0.f;
            for (int t = 0; t < 13; ++t) s += poolP[tid*16 + t];
        }
        float mx = s;
        #pragma unroll
        for (int mk = 1; mk < 64; mk <<= 1) mx = fmaxf(mx, __shfl_xor(mx, mk));
        float e = (tid < TITLE) ? __expf(s - mx) : 0.f;
        float ssum = e;
        #pragma unroll
        for (int mk = 1; mk < 64; mk <<= 1) ssum += __shfl_xor(ssum, mk);
        if (tid < TITLE) alphaS[tid] = e / ssum;
    }
    __syncthreads();
    for (int dd = tid; dd < DD; dd += 256) {
        float a = 0.f;
        for (int t = 0; t < TITLE; ++t) a += alphaS[t] * bf2f(outS[t*408 + dd]);
        odst[dd] = a;
    }
}

// ---------------------------------------------------------------------------
// K2a: m = h @ W via MFMA; 16 rows x half-n per block, grid (625,2).
// ---------------------------------------------------------------------------
__global__ __launch_bounds__(256) void mm_nodes_mfma(
    const float* __restrict__ A, const unsigned short* __restrict__ WT,
    unsigned short* __restrict__ Mo)
{
    __shared__ __align__(16) unsigned short aS[16 * 424];
    const int r0 = blockIdx.x * 16, ny = blockIdx.y, tid = threadIdx.x;
    const int w = tid >> 6, lane = tid & 63, g = lane >> 4, l15 = lane & 15;
    for (int i = tid; i < 16*424; i += 256) {
        int r = i / 424, c = i % 424;
        float v = (c < DD) ? A[(size_t)(r0 + r)*DD + c] : 0.f;
        aS[i] = f2bf(v);
    }
    __syncthreads();
    const int tstart = ny * 13, tcnt = ny ? 12 : 13;
    for (int tt = w; tt < tcnt; tt += 4) {
        int t = tstart + tt;
        const unsigned short* wb = WT + (size_t)(t*16 + l15) * 424;
        f32x4 c0 = {0.f,0.f,0.f,0.f};
        #pragma unroll
        for (int ks = 0; ks < 13; ++ks) {
            bh8 a0 = *(const bh8*)&aS[l15*424 + ks*32 + g*8];
            bh8 b  = *(const bh8*)&wb[ks*32 + g*8];
            c0 = __builtin_amdgcn_mfma_f32_16x16x32_bf16(a0, b, c0, 0, 0, 0);
        }
        int d = t*16 + l15;
        #pragma unroll
        for (int r = 0; r < 4; ++r)
            Mo[(size_t)(r0 + g*4 + r)*DD + d] = f2bf(c0[r]);
    }
}

// ---------------------------------------------------------------------------
// CSR build: count -> exclusive scan -> cursor scatter
// ---------------------------------------------------------------------------
__global__ __launch_bounds__(256) void count_edges(
    const int* __restrict__ ei, int* __restrict__ cnt)
{
    int e = blockIdx.x * 256 + threadIdx.x;
    if (e < EE) atomicAdd(&cnt[ei[EE + e]], 1);
}

__global__ __launch_bounds__(256) void build_offsets(
    const int* __restrict__ cnt, int* __restrict__ off, int* __restrict__ cursor)
{
    __shared__ int csum[256];
    const int tid = threadIdx.x;
    const int chunk = (NN + 255) / 256;   // 40
    int s = 0;
    for (int i = 0; i < chunk; ++i) {
        int idx = tid * chunk + i;
        if (idx < NN) s += cnt[idx];
    }
    csum[tid] = s;
    __syncthreads();
    if (tid == 0) {
        int run = 0;
        for (int i = 0; i < 256; ++i) { int c = csum[i]; csum[i] = run; run += c; }
    }
    __syncthreads();
    int run = csum[tid];
    for (int i = 0; i < chunk; ++i) {
        int idx = tid * chunk + i;
        if (idx < NN) {
            off[idx] = run; cursor[idx] = run;
            run += cnt[idx];
        }
    }
}

__global__ __launch_bounds__(256) void fill_csr(
    const int* __restrict__ ei, int* __restrict__ cursor, int* __restrict__ srclist)
{
    int e = blockIdx.x * 256 + threadIdx.x;
    if (e < EE) {
        int d = ei[EE + e];
        int pos = atomicAdd(&cursor[d], 1);
        srclist[pos] = ei[e];
    }
}

// ---------------------------------------------------------------------------
// K2b: agg[node] = sum over incoming edges of m[src]  (m is bf16).
// dword loads (r17-proven win).
// ---------------------------------------------------------------------------
__global__ __launch_bounds__(256) void gather_agg(
    const unsigned short* __restrict__ m, const int* __restrict__ off,
    const int* __restrict__ cnt, const int* __restrict__ srclist,
    float* __restrict__ agg)
{
    __shared__ int sl[128];
    const int node = blockIdx.x, tid = threadIdx.x;
    const int o0 = off[node], deg = cnt[node];
    float acc0 = 0.f, acc1 = 0.f;
    const int d0 = 2*tid;               // active when tid < 200
    const bool act = (d0 < DD);
    for (int j0 = 0; j0 < deg; j0 += 128) {
        if (tid < 128 && j0 + tid < deg) sl[tid] = srclist[o0 + j0 + tid];
        __syncthreads();
        const int jn = (deg - j0 < 128) ? (deg - j0) : 128;
        if (act) {
            for (int j = 0; j < jn; ++j) {
                const unsigned int u =
                    *(const unsigned int*)&m[(size_t)sl[j] * DD + d0];
                acc0 += bf2f((unsigned short)(u & 0xffffu));
                acc1 += bf2f((unsigned short)(u >> 16));
            }
        }
        __syncthreads();
    }
    if (act) {
        agg[(size_t)node * DD + d0]     = acc0;
        agg[(size_t)node * DD + d0 + 1] = acc1;
    }
}

// ---------------------------------------------------------------------------
// K2c: GRU cell via MFMA; 16 rows x half-n per block, grid (625,2).
// ---------------------------------------------------------------------------
__global__ __launch_bounds__(256) void gru_step_mfma(
    const float* __restrict__ agg, const float* __restrict__ hin,
    const unsigned short* __restrict__ wihT, const unsigned short* __restrict__ whhT,
    const float* __restrict__ bih, const float* __restrict__ bhh,
    float* __restrict__ hout)
{
    __shared__ __align__(16) unsigned short aggS[16 * 424];
    __shared__ __align__(16) unsigned short hS[16 * 424];
    const int r0 = blockIdx.x * 16, ny = blockIdx.y, tid = threadIdx.x;
    const int w = tid >> 6, lane = tid & 63, g = lane >> 4, l15 = lane & 15;
    for (int i = tid; i < 16*424; i += 256) {
        int r = i / 424, c = i % 424;
        float va = 0.f, vh = 0.f;
        if (c < DD) {
            va = agg[(size_t)(r0 + r)*DD + c];
            vh = hin[(size_t)(r0 + r)*DD + c];
        }
        aggS[i] = f2bf(va); hS[i] = f2bf(vh);
    }
    __syncthreads();
    const int tstart = ny * 13, tcnt = ny ? 12 : 13;
    for (int tt = w; tt < tcnt; tt += 4) {
        int t = tstart + tt;
        int d = t*16 + l15;
        const unsigned short* bri = wihT + (size_t)d * 424;
        const unsigned short* bzi = wihT + (size_t)(400 + d) * 424;
        const unsigned short* bni = wihT + (size_t)(800 + d) * 424;
        const unsigned short* brh = whhT + (size_t)d * 424;
        const unsigned short* bzh = whhT + (size_t)(400 + d) * 424;
        const unsigned short* bnh = whhT + (size_t)(800 + d) * 424;
        f32x4 ir = {0.f,0.f,0.f,0.f}, iz = {0.f,0.f,0.f,0.f}, in_ = {0.f,0.f,0.f,0.f};
        f32x4 hr = {0.f,0.f,0.f,0.f}, hz = {0.f,0.f,0.f,0.f}, hn = {0.f,0.f,0.f,0.f};
        #pragma unroll
        for (int ks = 0; ks < 13; ++ks) {
            bh8 aa = *(const bh8*)&aggS[l15*424 + ks*32 + g*8];
            bh8 ah = *(const bh8*)&hS[l15*424 + ks*32 + g*8];
            bh8 b0 = *(const bh8*)&bri[ks*32 + g*8];
            bh8 b1 = *(const bh8*)&bzi[ks*32 + g*8];
            bh8 b2 = *(const bh8*)&bni[ks*32 + g*8];
            bh8 b3 = *(const bh8*)&brh[ks*32 + g*8];
            bh8 b4 = *(const bh8*)&bzh[ks*32 + g*8];
            bh8 b5 = *(const bh8*)&bnh[ks*32 + g*8];
            ir  = __builtin_amdgcn_mfma_f32_16x16x32_bf16(aa, b0, ir,  0, 0, 0);
            iz  = __builtin_amdgcn_mfma_f32_16x16x32_bf16(aa, b1, iz,  0, 0, 0);
            in_ = __builtin_amdgcn_mfma_f32_16x16x32_bf16(aa, b2, in_, 0, 0, 0);
            hr  = __builtin_amdgcn_mfma_f32_16x16x32_bf16(ah, b3, hr,  0, 0, 0);
            hz  = __builtin_amdgcn_mfma_f32_16x16x32_bf16(ah, b4, hz,  0, 0, 0);
            hn  = __builtin_amdgcn_mfma_f32_16x16x32_bf16(ah, b5, hn,  0, 0, 0);
        }
        float bir = bih[d], biz = bih[400+d], bin = bih[800+d];
        float bhr = bhh[d], bhz = bhh[400+d], bhn = bhh[800+d];
        #pragma unroll
        for (int r = 0; r < 4; ++r) {
            int grow = r0 + g*4 + r;
            float hl = hin[(size_t)grow*DD + d];
            float rg = 1.f/(1.f + __expf(-(ir[r]+bir + hr[r]+bhr)));
            float zg = 1.f/(1.f + __expf(-(iz[r]+biz + hz[r]+bhz)));
            float ng = tanhf(in_[r]+bin + rg*(hn[r]+bhn));
            hout[(size_t)grow*DD + d] = (1.f-zg)*ng + zg*hl;
        }
    }
}

// ---------------------------------------------------------------------------
// K3a: clicked_total = concat(x_enc[midx], h[midx])*mask @ w_click + b_click
// ---------------------------------------------------------------------------
__global__ __launch_bounds__(256) void clicked_mm(
    const int* __restrict__ map, const float* __restrict__ xe,
    const float* __restrict__ hg, const float* __restrict__ wc,
    const float* __restrict__ bc, float* __restrict__ ct)
{
    __shared__ float a[8][2*DD];
    const int r0 = blockIdx.x * 8, tid = threadIdx.x;
    for (int i = tid; i < 8*2*DD; i += 256) {
        int r = i/(2*DD), k = i%(2*DD);
        int mi = map[r0 + r];
        float v = 0.f;
        if (mi >= 0) v = (k < DD) ? xe[(size_t)mi*DD + k] : hg[(size_t)mi*DD + (k-DD)];
        a[r][k] = v;
    }
    __syncthreads();
    for (int d = tid; d < DD; d += 256) {
        float acc[8] = {0,0,0,0,0,0,0,0};
        for (int k = 0; k < 2*DD; ++k) {
            float w = wc[(size_t)k*DD + d];
            #pragma unroll
            for (int r = 0; r < 8; ++r) acc[r] += a[r][k]*w;
        }
        float bb = bc[d];
        #pragma unroll
        for (int r = 0; r < 8; ++r) ct[(size_t)(r0+r)*DD + d] = acc[r] + bb;
    }
}

// ---------------------------------------------------------------------------
// K3b: uq/uk/uv = ct @ u_wq/u_wk/u_wv
// ---------------------------------------------------------------------------
__global__ __launch_bounds__(256) void user_qkv(
    const float* __restrict__ ct,
    const float* __restrict__ wq, const float* __restrict__ wk, const float* __restrict__ wv,
    float* __restrict__ uq, float* __restrict__ uk, float* __restrict__ uv)
{
    __shared__ float a[8][DD];
    const int r0 = blockIdx.x * 8, tid = threadIdx.x;
    for (int i = tid; i < 8*DD; i += 256)
        a[i/DD][i%DD] = ct[(size_t)(r0 + i/DD)*DD + i%DD];
    __syncthreads();
    for (int d = tid; d < DD; d += 256) {
        float aq[8]={0,0,0,0,0,0,0,0}, ak[8]={0,0,0,0,0,0,0,0}, av[8]={0,0,0,0,0,0,0,0};
        for (int k = 0; k < DD; ++k) {
            float wq_ = wq[(size_t)k*DD + d];
            float wk_ = wk[(size_t)k*DD + d];
            float wv_ = wv[(size_t)k*DD + d];
            #pragma unroll
            for (int r = 0; r < 8; ++r) {
                float x = a[r][k];
                aq[r] += x*wq_; ak[r] += x*wk_; av[r] += x*wv_;
            }
        }
        #pragma unroll
        for (int r = 0; r < 8; ++r) {
            uq[(size_t)(r0+r)*DD + d] = aq[r];
            uk[(size_t)(r0+r)*DD + d] = ak[r];
            uv[(size_t)(r0+r)*DD + d] = av[r];
        }
    }
}

// ---------------------------------------------------------------------------
// K3c: masked MHSA per (batch, head); block = 64 threads
// ---------------------------------------------------------------------------
__global__ __launch_bounds__(64) void user_attn(
    const float* __restrict__ uq, const float* __restrict__ uk,
    const float* __restrict__ uv, const int* __restrict__ map,
    float* __restrict__ uo)
{
    const int b = blockIdx.x / HH, h = blockIdx.x % HH, tid = threadIdx.x;
    __shared__ float q[NCK][DHD], k[NCK][DHD], v[NCK][DHD];
    __shared__ float sc[NCK][NCK+2];
    __shared__ float biasl[NCK];
    for (int i = tid; i < NCK*DHD; i += 64) {
        int c = i/DHD, d = i%DHD;
        size_t base = ((size_t)b*NCK + c)*DD + h*DHD + d;
        q[c][d] = uq[base]; k[c][d] = uk[base]; v[c][d] = uv[base];
    }
    for (int i = tid; i < NCK; i += 64)
        biasl[i] = (map[b*NCK + i] >= 0) ? 0.f : -1e9f;
    __syncthreads();
    for (int i = tid; i < NCK*NCK; i += 64) {
        int t = i/NCK, k2 = i%NCK;
        float s = 0.f;
        #pragma unroll
        for (int d4 = 0; d4 < 5; ++d4) {
            const float4 qa = *(const float4*)&q[t][d4*4];
            const float4 kb = *(const float4*)&k[k2][d4*4];
            s += qa.x*kb.x + qa.y*kb.y + qa.z*kb.z + qa.w*kb.w;
        }
        sc[t][k2] = s * 0.2236067977f + biasl[k2];
    }
    __syncthreads();
    if (tid < NCK) {
        float mx = -1e30f;
        for (int k2 = 0; k2 < NCK; ++k2) mx = fmaxf(mx, sc[tid][k2]);
        float ssum = 0.f;
        for (int k2 = 0; k2 < NCK; ++k2) { float e = __expf(sc[tid][k2]-mx); sc[tid][k2] = e; ssum += e; }
        float inv = 1.f/ssum;
        for (int k2 = 0; k2 < NCK; ++k2) sc[tid][k2] *= inv;
    }
    __syncthreads();
    for (int i = tid; i < NCK*DHD; i += 64) {
        int t = i/DHD, d = i%DHD;
        float o = 0.f;
        for (int k2 = 0; k2 < NCK; ++k2) o += sc[t][k2]*v[k2][d];
        uo[((size_t)b*NCK + t)*DD + h*DHD + d] = o;
    }
}

// ---------------------------------------------------------------------------
// K3d-1: pool scores via MFMA: alphaRaw[row] = tanh(uo[row]@uwp) @ uqp
// ---------------------------------------------------------------------------
__global__ __launch_bounds__(256) void pool_scores_mfma(
    const float* __restrict__ uo, const unsigned short* __restrict__ uwpT,
    const float* __restrict__ uqp, float* __restrict__ alphaRaw)
{
    __shared__ __align__(16) unsigned short aS[16 * 424];
    __shared__ float poolB[16][16];
    const int r0 = blockIdx.x * 16, tid = threadIdx.x;
    const int w = tid >> 6, lane = tid & 63, g = lane >> 4, l15 = lane & 15;
    for (int i = tid; i < 16*424; i += 256) {
        int r = i / 424, c = i % 424;
        float v = (c < DD) ? uo[(size_t)(r0 + r)*DD + c] : 0.f;
        aS[i] = f2bf(v);
    }
    if (tid < 256) poolB[tid/16][tid%16] = 0.f;
    __syncthreads();
    for (int t = w; t < 13; t += 4) {
        const unsigned short* wb = uwpT + (size_t)(t*16 + l15) * 416;
        bh8 bfr[13];
        #pragma unroll
        for (int ks = 0; ks < 13; ++ks)
            bfr[ks] = *(const bh8*)&wb[ks*32 + g*8];
        __builtin_amdgcn_sched_barrier(0);
        f32x4 c0 = {0.f,0.f,0.f,0.f};
        #pragma unroll
        for (int ks = 0; ks < 13; ++ks) {
            bh8 a0 = *(const bh8*)&aS[l15*424 + ks*32 + g*8];
            c0 = __builtin_amdgcn_mfma_f32_16x16x32_bf16(a0, bfr[ks], c0, 0, 0, 0);
        }
        int n = t*16 + l15;
        float qpn = (n < PP) ? uqp[n] : 0.f;
        #pragma unroll
        for (int r = 0; r < 4; ++r) {
            float v = tanhf(c0[r]) * qpn;
            #pragma unroll
            for (int mk = 1; mk < 16; mk <<= 1) v += __shfl_xor(v, mk);
            if (l15 == 0) poolB[g*4 + r][t] = v;
        }
    }
    __syncthreads();
    if (tid < 16) {
        float s = 0.f;
        for (int t = 0; t < 13; ++t) s += poolB[tid][t];
        alphaRaw[r0 + tid] = s;
    }
}

// ---------------------------------------------------------------------------
// K3d-2: masked softmax over alphaRaw + weighted sum -> user_emb
// ---------------------------------------------------------------------------
__global__ __launch_bounds__(256) void user_finalize(
    const float* __restrict__ alphaRaw, const int* __restrict__ map,
    const float* __restrict__ uo, float* __restrict__ user_emb)
{
    const int b = blockIdx.x, tid = threadIdx.x;
    __shared__ float alpha[64];
    if (tid < 64) {
        float a = -1e30f;
        if (tid < NCK)
            a = alphaRaw[b*NCK + tid] + ((map[b*NCK + tid] >= 0) ? 0.f : -1e9f);
        float mx = a;
        #pragma unroll
        for (int mk = 1; mk < 64; mk <<= 1) mx = fmaxf(mx, __shfl_xor(mx, mk));
        float e = (tid < NCK) ? __expf(a - mx) : 0.f;
        float ssum = e;
        #pragma unroll
        for (int mk = 1; mk < 64; mk <<= 1) ssum += __shfl_xor(ssum, mk);
        if (tid < NCK) alpha[tid] = e / ssum;
    }
    __syncthreads();
    for (int d = tid; d < DD; d += 256) {
        float acc = 0.f;
        for (int t = 0; t < NCK; ++t) acc += alpha[t] * uo[((size_t)b*NCK + t)*DD + d];
        user_emb[(size_t)b*DD + d] = acc;
    }
}

// ---------------------------------------------------------------------------
// K5: candidate scoring + NCE loss; single block
// ---------------------------------------------------------------------------
__global__ __launch_bounds__(256) void score_loss(
    const float* __restrict__ cr, const float* __restrict__ cf,
    const float* __restrict__ ue, const int* __restrict__ label,
    float* __restrict__ dout)
{
    __shared__ float sr[BB][NCAND], sf[BB][NCAND], red[BB];
    const int tid = threadIdx.x;
    for (int i = tid; i < 2*BB*NCAND; i += 256) {
        int which = i / (BB*NCAND);
        int r = i % (BB*NCAND);
        int b = r / NCAND, c = r % NCAND;
        const float* ce = (which ? cf : cr) + (size_t)r*DD;
        const float* u = ue + (size_t)b*DD;
        float s = 0.f;
        for (int d = 0; d < DD; ++d) s += ce[d]*u[d];
        if (which) sf[b][c] = s; else sr[b][c] = s;
        dout[1 + i] = s;
    }
    __syncthreads();
    if (tid < BB) {
        int b = tid;
        float mr = -1e30f, mf = -1e30f;
        for (int c = 0; c < NCAND; ++c) { mr = fmaxf(mr, sr[b][c]); mf = fmaxf(mf, sf[b][c]); }
        float er = 0.f, ef = 0.f;
        for (int c = 0; c < NCAND; ++c) { er += expf(sr[b][c]-mr); ef += expf(sf[b][c]-mf); }
        float lser = logf(er)+mr, lsef = logf(ef)+mf;
        int lab = label[b]; lab = lab < 0 ? 0 : (lab > NCAND-1 ? NCAND-1 : lab);
        float crb = lser - sr[b][lab];
        float cfb = 0.f;
        for (int c = 0; c < NCAND; ++c) cfb += (lsef - sf[b][c]);
        red[tid] = crb + 0.5f * (cfb / (float)NCAND);
    }
    __syncthreads();
    if (tid == 0) {
        float L = 0.f;
        for (int b = 0; b < BB; ++b) L += red[b];
        dout[0] = L / (float)BB;
    }
}

// ---------------------------------------------------------------------------
extern "C" void kernel_launch(void* const* d_in, const int* in_sizes, int n_in,
                              void* d_out, int out_size, void* d_ws, size_t ws_size,
                              hipStream_t stream) {
    (void)in_sizes; (void)n_in; (void)out_size; (void)ws_size;
    const int*   sub_x  = (const int*)d_in[0];
    const int*   edge   = (const int*)d_in[1];
    const int*   mapi   = (const int*)d_in[2];
    const int*   cand   = (const int*)d_in[3];
    const int*   fcand  = (const int*)d_in[4];
    const int*   label  = (const int*)d_in[5];
    const float* glove  = (const float*)d_in[6];
    const float* nwq    = (const float*)d_in[7];
    const float* nwk    = (const float*)d_in[8];
    const float* nwv    = (const float*)d_in[9];
    const float* nwp    = (const float*)d_in[10];
    const float* nqp    = (const float*)d_in[11];
    const float* ggc    = (const float*)d_in[12];
    const float* wih    = (const float*)d_in[13];
    const float* whh    = (const float*)d_in[14];
    const float* bih    = (const float*)d_in[15];
    const float* bhh    = (const float*)d_in[16];
    const float* wclick = (const float*)d_in[17];
    const float* bclick = (const float*)d_in[18];
    const float* uwq    = (const float*)d_in[19];
    const float* uwk    = (const float*)d_in[20];
    const float* uwv    = (const float*)d_in[21];
    const float* uwp    = (const float*)d_in[22];
    const float* uqp    = (const float*)d_in[23];

    // workspace layout (floats); ws_size = 256 MiB
    float* ws     = (float*)d_ws;
    float* x_enc  = ws;                       // 4,000,000 f
    float* hbuf   = ws + 4000000;             // 4,000,000 f
    float* region = ws + 8000000;             // 8,000,000 f shared region
    unsigned short* mbufBF = (unsigned short*)region;   // GGC: m bf16 [NN][400]
    float* aggbuf = region + 4000000;         // GGC: agg f32
    // after GGC, region reused:
    float* ct   = region;                     // 1,280,000
    float* uq   = region + 1280000;
    float* uk   = region + 2560000;
    float* uv   = region + 3840000;
    float* uo   = region + 5120000;           // 1,280,000
    float* user = region + 6400000;           // 25,600
    float* alphaRaw = region + 6430000;       // 3,200
    // int area at byte offset 64 MB
    int* ibase   = (int*)((char*)d_ws + (size_t)64*1024*1024);
    int* cnt     = ibase;                     // 10,000
    int* off     = ibase + 10000;             // 10,000
    int* cursor  = ibase + 20000;             // 10,000
    int* srclist = ibase + 30000;             // 200,000
    // bf16 prepped weights
    unsigned short* Wt   = (unsigned short*)(ws + 17100000);  // 1200*320 sh
    unsigned short* wpT  = (unsigned short*)(ws + 17300000);  // 208*416 sh
    unsigned short* wggT = (unsigned short*)(ws + 17400000);  // 3*400*424 sh
    unsigned short* wihT = (unsigned short*)(ws + 17700000);  // 1200*424 sh
    unsigned short* whhT = (unsigned short*)(ws + 18000000);  // 1200*424 sh
    unsigned short* uwpT = (unsigned short*)(ws + 18300000);  // 208*416 sh
    float* hbuf2 = ws + 19000000;             // 4,000,000 f (GRU ping-pong)
    float* crnc  = ws + 23500000;             // 128,000 f
    float* cfnc  = ws + 23700000;             // 128,000 f

    // 0) prep transposed bf16 weights (tiny; L2-resident afterwards)
    prep_wt<<<1500, 256, 0, stream>>>(nwq, nwk, nwv, Wt);
    prep_wpt<<<338, 256, 0, stream>>>(nwp, wpT);
    prep_wpt<<<338, 256, 0, stream>>>(uwp, uwpT);
    prep_wgg<<<(3*400*424 + 255)/256, 256, 0, stream>>>(ggc, wggT);
    prep_gruw<<<(1200*424 + 255)/256, 256, 0, stream>>>(wih, whh, wihT, whhT);

    // 1) encode all nodes + candidates (one fused launch; r18-proven)
    news_enc<<<NN + 2*BB*NCAND, 256, 0, stream>>>(
        sub_x, cand, fcand, glove, Wt, wpT, nqp, x_enc, crnc, cfnc);

    // 1b) build CSR-by-destination once
    hipMemsetAsync(cnt, 0, NN*sizeof(int), stream);
    count_edges<<<(EE+255)/256, 256, 0, stream>>>(edge, cnt);
    build_offsets<<<1, 256, 0, stream>>>(cnt, off, cursor);
    fill_csr<<<(EE+255)/256, 256, 0, stream>>>(edge, cursor, srclist);

    // 2) GatedGraphConv x3
    const float* hin = x_enc;
    float* houts[3] = {hbuf, hbuf2, hbuf};
    for (int l = 0; l < 3; ++l) {
        mm_nodes_mfma<<<dim3(625,2), 256, 0, stream>>>(hin, wggT + (size_t)l*400*424, mbufBF);
        gather_agg<<<NN, 256, 0, stream>>>(mbufBF, off, cnt, srclist, aggbuf);
        gru_step_mfma<<<dim3(625,2), 256, 0, stream>>>(aggbuf, hin, wihT, whhT, bih, bhh, houts[l]);
        hin = houts[l];
    }

    // 3) click + user encoder  (final h is in hbuf)
    clicked_mm<<<(BB*NCK)/8, 256, 0, stream>>>(mapi, x_enc, hbuf, wclick, bclick, ct);
    user_qkv<<<(BB*NCK)/8, 256, 0, stream>>>(ct, uwq, uwk, uwv, uq, uk, uv);
    user_attn<<<BB*HH, 64, 0, stream>>>(uq, uk, uv, mapi, uo);
    pool_scores_mfma<<<(BB*NCK)/16, 256, 0, stream>>>(uo, uwpT, uqp, alphaRaw);
    user_finalize<<<BB, 256, 0, stream>>>(alphaRaw, mapi, uo, user);

    // 4) scores + loss
    score_loss<<<1, 256, 0, stream>>>(crnc, cfnc, user, label, (float*)d_out);
}